// Round 1
// baseline (815.225 us; speedup 1.0000x reference)
//
#include <hip/hip_runtime.h>
#include <hip/hip_bf16.h>

// Problem dims
#define B_  4
#define T_  256
#define U_  128
#define DE  512
#define DP  640
#define H_  512
#define V_  1024
#define M_  (B_*T_*U_)   // 131072 rows of the joint
#define BT_ (B_*T_)      // 1024
#define BU_ (B_*U_)      // 512

typedef float f32x4 __attribute__((ext_vector_type(4)));
typedef __bf16 bf16x8 __attribute__((ext_vector_type(8)));
typedef __attribute__((address_space(1))) char gchar;
typedef __attribute__((address_space(3))) char schar;

static __device__ __forceinline__ unsigned short f2bf(float f) {
    unsigned u = __float_as_uint(f);
    unsigned r = (u + 0x7fffu + ((u >> 16) & 1u)) >> 16;   // RNE
    return (unsigned short)r;
}

// ---------------------------------------------------------------------------
// fp32 projection GEMM: Y[M][N] = X[M][D] * W[N][D]^T + bias, 64x64 tile
// ---------------------------------------------------------------------------
__global__ void proj_kernel(const float* __restrict__ X, const float* __restrict__ W,
                            const float* __restrict__ bias, float* __restrict__ Y,
                            int M, int N, int D) {
    __shared__ float Xs[64][33];
    __shared__ float Ws[64][33];
    const int tid  = threadIdx.x;
    const int rowb = blockIdx.y * 64, colb = blockIdx.x * 64;
    const int ty = tid >> 4, tx = tid & 15;
    const int lr = tid >> 3, lc = (tid & 7) * 4;
    float acc[4][4] = {};
    for (int k0 = 0; k0 < D; k0 += 32) {
#pragma unroll
        for (int p = 0; p < 2; ++p) {
            float4 xv = *(const float4*)&X[(size_t)(rowb + p*32 + lr) * D + k0 + lc];
            float4 wv = *(const float4*)&W[(size_t)(colb + p*32 + lr) * D + k0 + lc];
            Xs[p*32+lr][lc+0] = xv.x; Xs[p*32+lr][lc+1] = xv.y;
            Xs[p*32+lr][lc+2] = xv.z; Xs[p*32+lr][lc+3] = xv.w;
            Ws[p*32+lr][lc+0] = wv.x; Ws[p*32+lr][lc+1] = wv.y;
            Ws[p*32+lr][lc+2] = wv.z; Ws[p*32+lr][lc+3] = wv.w;
        }
        __syncthreads();
#pragma unroll
        for (int kk = 0; kk < 32; ++kk) {
            float a[4], b[4];
#pragma unroll
            for (int i = 0; i < 4; ++i) { a[i] = Xs[ty*4+i][kk]; b[i] = Ws[tx*4+i][kk]; }
#pragma unroll
            for (int i = 0; i < 4; ++i)
#pragma unroll
                for (int j = 0; j < 4; ++j) acc[i][j] += a[i] * b[j];
        }
        __syncthreads();
    }
    float4 bv = *(const float4*)&bias[colb + tx*4];
#pragma unroll
    for (int i = 0; i < 4; ++i) {
        const size_t row = rowb + ty*4 + i;
        float4 o; o.x = acc[i][0]+bv.x; o.y = acc[i][1]+bv.y; o.z = acc[i][2]+bv.z; o.w = acc[i][3]+bv.w;
        *(float4*)&Y[row * N + colb + tx*4] = o;
    }
}

// ---------------------------------------------------------------------------
// fp32 -> bf16 raw conversion (for W_out)
// ---------------------------------------------------------------------------
__global__ void tobf16_kernel(const float* __restrict__ w, unsigned short* __restrict__ o, int n) {
    int i = (blockIdx.x * blockDim.x + threadIdx.x) * 4;
    if (i < n) {
        float4 v = *(const float4*)&w[i];
        ushort4 u;
        u.x = f2bf(v.x); u.y = f2bf(v.y); u.z = f2bf(v.z); u.w = f2bf(v.w);
        *(ushort4*)&o[i] = u;
    }
}

// ---------------------------------------------------------------------------
// joint row r = bt*U + u :  y = LN(relu(enc[bt] + pred[b*U+u])) * gamma + beta
// one wave per row; output bf16 raw
// ---------------------------------------------------------------------------
__global__ void ln_kernel(const float* __restrict__ enc, const float* __restrict__ pred,
                          const float* __restrict__ gamma, const float* __restrict__ beta,
                          unsigned short* __restrict__ joint) {
    const int lane = threadIdx.x & 63;
    const int wid  = (blockIdx.x * blockDim.x + threadIdx.x) >> 6;
    const int nw   = (gridDim.x * blockDim.x) >> 6;
    const int c0 = lane * 4, c1 = 256 + lane * 4;
    const float4 g0  = *(const float4*)&gamma[c0], g1  = *(const float4*)&gamma[c1];
    const float4 be0 = *(const float4*)&beta[c0],  be1 = *(const float4*)&beta[c1];
    for (int r = wid; r < M_; r += nw) {
        const int bt = r >> 7, u = r & 127, b = bt >> 8;
        const float4 e0 = *(const float4*)&enc[(size_t)bt * H_ + c0];
        const float4 e1 = *(const float4*)&enc[(size_t)bt * H_ + c1];
        const float4 p0 = *(const float4*)&pred[(size_t)(b*U_ + u) * H_ + c0];
        const float4 p1 = *(const float4*)&pred[(size_t)(b*U_ + u) * H_ + c1];
        float v[8];
        v[0] = fmaxf(e0.x + p0.x, 0.f); v[1] = fmaxf(e0.y + p0.y, 0.f);
        v[2] = fmaxf(e0.z + p0.z, 0.f); v[3] = fmaxf(e0.w + p0.w, 0.f);
        v[4] = fmaxf(e1.x + p1.x, 0.f); v[5] = fmaxf(e1.y + p1.y, 0.f);
        v[6] = fmaxf(e1.z + p1.z, 0.f); v[7] = fmaxf(e1.w + p1.w, 0.f);
        float s = 0.f, q = 0.f;
#pragma unroll
        for (int j = 0; j < 8; ++j) { s += v[j]; q += v[j]*v[j]; }
#pragma unroll
        for (int off = 32; off; off >>= 1) { s += __shfl_xor(s, off); q += __shfl_xor(q, off); }
        const float mean = s * (1.f / H_);
        const float var  = q * (1.f / H_) - mean * mean;
        const float rstd = rsqrtf(var + 1e-5f);
        ushort4 o0, o1;
        o0.x = f2bf((v[0]-mean)*rstd*g0.x + be0.x); o0.y = f2bf((v[1]-mean)*rstd*g0.y + be0.y);
        o0.z = f2bf((v[2]-mean)*rstd*g0.z + be0.z); o0.w = f2bf((v[3]-mean)*rstd*g0.w + be0.w);
        o1.x = f2bf((v[4]-mean)*rstd*g1.x + be1.x); o1.y = f2bf((v[5]-mean)*rstd*g1.y + be1.y);
        o1.z = f2bf((v[6]-mean)*rstd*g1.z + be1.z); o1.w = f2bf((v[7]-mean)*rstd*g1.w + be1.w);
        *(ushort4*)&joint[(size_t)r * H_ + c0] = o0;
        *(ushort4*)&joint[(size_t)r * H_ + c1] = o1;
    }
}

// ---------------------------------------------------------------------------
// out[M][V] = joint[M][H](bf16) * Wout[V][H](bf16)^T + b_out   (fp32 out)
// m97 structure: 128x128 tile, BK=64, 4 waves (2x2), global_load_lds width 16
// ---------------------------------------------------------------------------
__global__ __launch_bounds__(256, 2) void out_gemm(
        const unsigned short* __restrict__ Aj, const unsigned short* __restrict__ Wb,
        const float* __restrict__ bias, float* __restrict__ out) {
    __shared__ char As[128 * 64 * 2];
    __shared__ char Bs[128 * 64 * 2];
    const int tid  = threadIdx.x;
    const int lane = tid & 63, w = tid >> 6;
    const int rowb = blockIdx.y << 7;       // 1024 row panels
    const int colb = blockIdx.x << 7;       // 8 col blocks
    const int wm = w >> 1, wn = w & 1;      // 2x2 wave grid, 64x64 per wave
    f32x4 acc[4][4] = {};
    const int lr  = lane >> 3;              // row within 8-row group
    const int lcB = (lane & 7) * 16;        // byte offset within 128B row
    const size_t arow0 = (size_t)(rowb + w*8 + lr);
    const size_t brow0 = (size_t)(colb + w*8 + lr);

    for (int k0 = 0; k0 < H_; k0 += 64) {
        const char* ga = (const char*)Aj + (arow0 * H_ + k0) * 2 + lcB;
        const char* gb = (const char*)Wb + (brow0 * H_ + k0) * 2 + lcB;
#pragma unroll
        for (int i = 0; i < 4; ++i) {
            __builtin_amdgcn_global_load_lds((const gchar*)(ga + (size_t)i * 32 * (H_*2)),
                                             (schar*)(As + (w*8 + i*32) * 128), 16, 0, 0);
            __builtin_amdgcn_global_load_lds((const gchar*)(gb + (size_t)i * 32 * (H_*2)),
                                             (schar*)(Bs + (w*8 + i*32) * 128), 16, 0, 0);
        }
        __syncthreads();
#pragma unroll
        for (int ks = 0; ks < 2; ++ks) {
            const int kb = ks * 64;         // byte offset: 32 bf16 per k-slice
            bf16x8 a[4], b[4];
#pragma unroll
            for (int mi = 0; mi < 4; ++mi)
                a[mi] = *(const bf16x8*)(As + (wm*64 + mi*16 + (lane & 15)) * 128 + kb + (lane >> 4) * 16);
#pragma unroll
            for (int ni = 0; ni < 4; ++ni)
                b[ni] = *(const bf16x8*)(Bs + (wn*64 + ni*16 + (lane & 15)) * 128 + kb + (lane >> 4) * 16);
#pragma unroll
            for (int mi = 0; mi < 4; ++mi)
#pragma unroll
                for (int ni = 0; ni < 4; ++ni)
                    acc[mi][ni] = __builtin_amdgcn_mfma_f32_16x16x32_bf16(a[mi], b[ni], acc[mi][ni], 0, 0, 0);
        }
        __syncthreads();
    }
    const int r4 = (lane >> 4) * 4;
    const int cn = lane & 15;
#pragma unroll
    for (int ni = 0; ni < 4; ++ni) {
        const int col = colb + wn*64 + ni*16 + cn;
        const float bv = bias[col];
#pragma unroll
        for (int mi = 0; mi < 4; ++mi) {
            const size_t row = (size_t)rowb + wm*64 + mi*16 + r4;
            float* po = out + row * V_ + col;
#pragma unroll
            for (int r = 0; r < 4; ++r) po[(size_t)r * V_] = acc[mi][ni][r] + bv;
        }
    }
}

// ---------------------------------------------------------------------------
extern "C" void kernel_launch(void* const* d_in, const int* in_sizes, int n_in,
                              void* d_out, int out_size, void* d_ws, size_t ws_size,
                              hipStream_t stream) {
    const float* enc_in  = (const float*)d_in[0];
    const float* pred_in = (const float*)d_in[1];
    const float* W_enc   = (const float*)d_in[2];
    const float* b_enc   = (const float*)d_in[3];
    const float* W_pred  = (const float*)d_in[4];
    const float* b_pred  = (const float*)d_in[5];
    const float* gamma   = (const float*)d_in[6];
    const float* beta    = (const float*)d_in[7];
    const float* W_out   = (const float*)d_in[8];
    const float* b_out   = (const float*)d_in[9];
    float* out = (float*)d_out;

    char* ws = (char*)d_ws;                                     // need 132 MB
    float*          encP  = (float*)ws;                         // [1024][512] f32, 2 MB
    float*          predP = (float*)(ws + (2u << 20));          // [512][512]  f32, 1 MB
    unsigned short* WoutB = (unsigned short*)(ws + (3u << 20)); // [1024][512] bf16, 1 MB
    unsigned short* joint = (unsigned short*)(ws + (4u << 20)); // [131072][512] bf16, 128 MB

    proj_kernel<<<dim3(H_/64, BT_/64), 256, 0, stream>>>(enc_in,  W_enc,  b_enc,  encP,  BT_, H_, DE);
    proj_kernel<<<dim3(H_/64, BU_/64), 256, 0, stream>>>(pred_in, W_pred, b_pred, predP, BU_, H_, DP);
    tobf16_kernel<<<(V_*H_)/(256*4), 256, 0, stream>>>(W_out, WoutB, V_*H_);
    ln_kernel<<<2048, 256, 0, stream>>>(encP, predP, gamma, beta, joint);
    out_gemm<<<dim3(V_/128, M_/128), 256, 0, stream>>>(joint, WoutB, b_out, out);
}